// Round 5
// baseline (930.105 us; speedup 1.0000x reference)
//
#include <hip/hip_runtime.h>

#define BB   256
#define TT   512
#define EMBD 64
#define CHARD 50
#define DIN  114
#define RNN  128
#define NG   512   // 4*RNN
#define TAGS 9

typedef __bf16 bf16x8 __attribute__((ext_vector_type(8)));
typedef float  f32x4  __attribute__((ext_vector_type(4)));

static __device__ __forceinline__ unsigned short f2bf(float f) {
  unsigned int u = __float_as_uint(f);
  unsigned int r = (u + 0x7FFFu + ((u >> 16) & 1u)) >> 16;  // RNE
  return (unsigned short)r;
}
static __device__ __forceinline__ void gl_lds16(const void* g, void* l) {
  __builtin_amdgcn_global_load_lds(
      (const __attribute__((address_space(1))) unsigned int*)g,
      (__attribute__((address_space(3))) unsigned int*)l, 16, 0, 0);
}

// ---------------- x = concat(E[inputs], char_emb) padded to 128, bf16 ----------------
__global__ void k_build_x(const int* __restrict__ inp, const float* __restrict__ ch,
                          const float* __restrict__ E, unsigned short* __restrict__ x) {
  int idx = blockIdx.x * 256 + threadIdx.x;   // over B*T*128
  int k   = idx & 127;
  int row = idx >> 7;                          // b*T+t
  float v;
  if (k < EMBD)      v = E[inp[row] * EMBD + k];
  else if (k < DIN)  v = ch[row * CHARD + (k - EMBD)];
  else               v = 0.f;
  x[idx] = f2bf(v);
}

// ------- weights -> [n][k] bf16 (B-frag friendly); block 512 builds WdT [16][256] -------
__global__ void k_prep_w(const float* __restrict__ Wx_f, const float* __restrict__ Wh_f,
                         const float* __restrict__ Wx_b, const float* __restrict__ Wh_b,
                         const float* __restrict__ Wd,
                         unsigned short* __restrict__ WxT, unsigned short* __restrict__ WhT,
                         unsigned short* __restrict__ WdT) {
  if (blockIdx.x == 512) {
    for (int i = threadIdx.x; i < 16 * 256; i += 256) {
      int n = i >> 8, k = i & 255;
      WdT[i] = (n < TAGS) ? f2bf(Wd[k * TAGS + n]) : (unsigned short)0;
    }
    return;
  }
  int idx = blockIdx.x * 256 + threadIdx.x;   // over 2*512*128
  int dir = idx >> 16;
  int rem = idx & 65535;
  int n   = rem >> 7;
  int kk  = rem & 127;
  const float* Wx = dir ? Wx_b : Wx_f;
  const float* Wh = dir ? Wh_b : Wh_f;
  WxT[idx] = (kk < DIN) ? f2bf(Wx[kk * NG + n]) : (unsigned short)0;
  WhT[idx] = f2bf(Wh[kk * NG + n]);
}

__global__ void k_lengths(const int* __restrict__ labels, int* __restrict__ lengths) {
  int b = blockIdx.x, lane = threadIdx.x;
  int cnt = 0;
  for (int t = lane; t < TT; t += 64) cnt += (labels[b * TT + t] != 0);
  for (int o = 32; o > 0; o >>= 1) cnt += __shfl_down(cnt, o);
  if (lane == 0) lengths[b] = cnt;
}

// ==================== fused per-pass kernel ====================
// Blocks [0, lstm_n): BiLSTM recurrence for steps [s0, s1), 8 batch rows per
//   WG, 4 waves; h ring in swizzled LDS ([row][unit^row], 8 slots); z (f32,
//   bias included) loaded straight into MFMA accumulators; permlane32_swap
//   packs tile-1 rows onto lanes>=32 so all 64 lanes compute gates.
// Blocks [lstm_n, ...): z = x@Wx + b for the NEXT pass, written in exact
//   consumer record order. All barriers are __syncthreads() (memory-fenced).
__global__ __launch_bounds__(256, 1) void k_fused(
    const unsigned short* __restrict__ x,
    const unsigned short* __restrict__ WxT,
    const unsigned short* __restrict__ WhT,
    const float* __restrict__ b_f, const float* __restrict__ b_b,
    const float* __restrict__ zcons, float* __restrict__ zprod,
    unsigned short* __restrict__ hseq, float* __restrict__ cbuf,
    int lstm_n, int s0, int s1, int first, int zs0, int znsteps)
{
  __shared__ __align__(16) char LDS[32768];
  const int tid = threadIdx.x, w = tid >> 6, l = tid & 63;
  const int lq = l & 15, lg = l >> 4;

  if ((int)blockIdx.x < lstm_n) {
    // ---------------- LSTM consumer ----------------
    const int wg = blockIdx.x, dir = wg >> 5, rg = wg & 31, b0 = rg * 8;
    const unsigned short* WhD = WhT + dir * (NG * 128);
    unsigned short* hout = hseq + (size_t)dir * ((size_t)BB * TT * 128);
    char* ring = LDS;  // 8 slots x 2048 B, swizzled [row][128] bf16

    // Wh B-fragments: tiles (g, j): n = g*128 + w*32 + j*16 + lq, k = kt*32+lg*8
    bf16x8 wh[4][2][4];
    #pragma unroll
    for (int g = 0; g < 4; ++g)
      #pragma unroll
      for (int j = 0; j < 2; ++j) {
        int n = g * RNN + w * 32 + j * 16 + lq;
        #pragma unroll
        for (int kt = 0; kt < 4; ++kt)
          wh[g][j][kt] = *reinterpret_cast<const bf16x8*>(WhD + n * 128 + kt * 32 + lg * 8);
      }

    // per-thread gate mapping (after pack): hidden, rows (lg&1)*4+r
    const int hidden = w * 32 + (lg >> 1) * 16 + lq;
    const int ku  = hidden >> 3;
    const int inb = (hidden & 7) * 2;
    // A-frag read offsets (bytes within slot): row = l&7 (mirrored), k = kt*32+lg*8
    const int row7 = l & 7;
    int ro[4];
    #pragma unroll
    for (int kt = 0; kt < 4; ++kt)
      ro[kt] = (row7 * 16 + (((kt * 4) + lg) ^ row7)) * 16;

    // restore h(s0-1) into slot 7, c from cbuf (or zeros)
    if (tid < 128) {
      int row = tid >> 4, h16 = tid & 15;
      int unit = row * 16 + (h16 ^ row);
      if (first) {
        *reinterpret_cast<f32x4*>(ring + 7 * 2048 + unit * 16) = f32x4{0.f, 0.f, 0.f, 0.f};
      } else {
        int tprev = dir ? (TT - s0) : (s0 - 1);
        bf16x8 v = *reinterpret_cast<const bf16x8*>(
            hout + ((size_t)(b0 + row) * TT + tprev) * 128 + h16 * 8);
        *reinterpret_cast<bf16x8*>(ring + 7 * 2048 + unit * 16) = v;
      }
    }
    float c[4];
    #pragma unroll
    for (int r = 0; r < 4; ++r) {
      int rowc = (lg & 1) * 4 + r;
      c[r] = first ? 0.f : cbuf[(size_t)(dir * BB + b0 + rowc) * RNN + hidden];
    }
    __syncthreads();

    // z record pointer (f32): only lanes lg<2 load (valid D rows)
    const float* zrec = zcons + ((size_t)((dir * 32 + rg) * 4 + w)) * 1024 + (lg * 16 + lq) * 32;
    f32x4 zc[8];
    if (lg < 2) {
      #pragma unroll
      for (int i = 0; i < 8; ++i) zc[i] = *reinterpret_cast<const f32x4*>(zrec + i * 4);
    }

    for (int s = s0; s < s1; ++s) {
      // acc init from z (includes bias)
      f32x4 acc[4][2];
      #pragma unroll
      for (int g = 0; g < 4; ++g)
        #pragma unroll
        for (int j = 0; j < 2; ++j)
          acc[g][j] = (lg < 2) ? zc[g * 2 + j] : f32x4{0.f, 0.f, 0.f, 0.f};
      // prefetch next step's z
      {
        int sn = (s + 1 < s1) ? (s + 1) : (s1 - 1);
        if (lg < 2) {
          const float* zp = zrec + (size_t)(sn - s0) * 262144;
          #pragma unroll
          for (int i = 0; i < 8; ++i) zc[i] = *reinterpret_cast<const f32x4*>(zp + i * 4);
        }
      }

      // h fragments + 32 MFMA
      const char* rb = ring + ((s - 1) & 7) * 2048;
      bf16x8 hf[4];
      #pragma unroll
      for (int kt = 0; kt < 4; ++kt)
        hf[kt] = *reinterpret_cast<const bf16x8*>(rb + ro[kt]);
      #pragma unroll
      for (int kt = 0; kt < 4; ++kt)
        #pragma unroll
        for (int g = 0; g < 4; ++g) {
          acc[g][0] = __builtin_amdgcn_mfma_f32_16x16x32_bf16(hf[kt], wh[g][0][kt], acc[g][0], 0, 0, 0);
          acc[g][1] = __builtin_amdgcn_mfma_f32_16x16x32_bf16(hf[kt], wh[g][1][kt], acc[g][1], 0, 0, 0);
        }

      // coalesced hseq store of 4 finished steps (drained by syncthreads)
      if ((s & 3) == 0 && s > s0) {
        int sp = s - 4;
        #pragma unroll
        for (int j = 0; j < 2; ++j) {
          int u = tid + j * 256;
          int h16 = u & 15, tc = (u >> 4) & 3, row = u >> 6;
          int ss = sp + tc, t = dir ? (TT - 1 - ss) : ss;
          bf16x8 v = *reinterpret_cast<const bf16x8*>(
              ring + (ss & 7) * 2048 + (row * 16 + (h16 ^ row)) * 16);
          *reinterpret_cast<bf16x8*>(hout + ((size_t)(b0 + row) * TT + t) * 128 + h16 * 8) = v;
        }
      }

      // pack: lanes>=32 receive tile j=1 rows 0..7 from lanes<32
      float sw[4][4];
      #pragma unroll
      for (int g = 0; g < 4; ++g)
        #pragma unroll
        for (int r = 0; r < 4; ++r) {
          float d = acc[g][1][r], srcv = acc[g][1][r];
          asm volatile("v_permlane32_swap_b32 %0, %1" : "+v"(d), "+v"(srcv));
          sw[g][r] = d;
        }

      // gates (fused-rcp, exact): 5 exp + 2 rcp per group
      char* ws_ = ring + (s & 7) * 2048;
      #pragma unroll
      for (int r = 0; r < 4; ++r) {
        float zi = (lg < 2) ? acc[0][0][r] : sw[0][r];
        float zf = (lg < 2) ? acc[1][0][r] : sw[1][r];
        float zg = (lg < 2) ? acc[2][0][r] : sw[2][r];
        float zo = (lg < 2) ? acc[3][0][r] : sw[3][r];
        zi = fminf(20.f, fmaxf(-20.f, zi));
        zf = fminf(20.f, fmaxf(-20.f, zf));
        zg = fminf(20.f, fmaxf(-20.f, zg));
        zo = fminf(20.f, fmaxf(-20.f, zo));
        float ei = __expf(-zi), ef = __expf(-zf), eo = __expf(-zo);
        float g2 = __expf(2.f * zg);
        float P   = (1.f + ei) * (g2 + 1.f);
        float efp = 1.f + ef;
        float num = c[r] * P + efp * (g2 - 1.f);
        float cn  = num * __builtin_amdgcn_rcpf(efp * P);
        c[r] = cn;
        float cc = fminf(20.f, fmaxf(-20.f, cn));
        float ec = __expf(2.f * cc);
        float hn = (ec - 1.f) * __builtin_amdgcn_rcpf((1.f + eo) * (ec + 1.f));
        int rowr = (lg & 1) * 4 + r;
        int unit = rowr * 16 + (ku ^ rowr);
        *reinterpret_cast<unsigned short*>(ws_ + unit * 16 + inb) = f2bf(hn);
      }
      __syncthreads();
    }

    // final 4-step store + c save
    {
      int sp = s1 - 4;
      #pragma unroll
      for (int j = 0; j < 2; ++j) {
        int u = tid + j * 256;
        int h16 = u & 15, tc = (u >> 4) & 3, row = u >> 6;
        int ss = sp + tc, t = dir ? (TT - 1 - ss) : ss;
        bf16x8 v = *reinterpret_cast<const bf16x8*>(
            ring + (ss & 7) * 2048 + (row * 16 + (h16 ^ row)) * 16);
        *reinterpret_cast<bf16x8*>(hout + ((size_t)(b0 + row) * TT + t) * 128 + h16 * 8) = v;
      }
    }
    #pragma unroll
    for (int r = 0; r < 4; ++r) {
      int rowc = (lg & 1) * 4 + r;
      cbuf[(size_t)(dir * BB + b0 + rowc) * RNN + hidden] = c[r];
    }
  } else {
    // ---------------- zgemm producer (next pass) ----------------
    if (znsteps <= 0) return;
    const int TCHN = znsteps >> 4;
    const int zb = blockIdx.x - lstm_n;
    const int per = 16 * TCHN;
    const int dir = zb / per;
    const int rem = zb % per;
    const int rg2 = rem / TCHN, tch = rem % TCHN;
    const int b0p = rg2 * 16;
    const int sb  = zs0 + tch * 16;

    const unsigned short* WxD = WxT + dir * (NG * 128);
    const float* bias = dir ? b_b : b_f;
    unsigned short* xr = (unsigned short*)LDS;  // [2 buf][4 sc][4 kt][64 l][8]

    bf16x8 wx[4][2][4];
    float  bs[4][2];
    #pragma unroll
    for (int g = 0; g < 4; ++g)
      #pragma unroll
      for (int j = 0; j < 2; ++j) {
        int n = g * RNN + w * 32 + j * 16 + lq;
        bs[g][j] = bias[n];
        #pragma unroll
        for (int kt = 0; kt < 4; ++kt)
          wx[g][j][kt] = *reinterpret_cast<const bf16x8*>(WxD + n * 128 + kt * 32 + lg * 8);
      }

    auto stage = [&](int ci) {
      int buf = ci & 1;
      #pragma unroll
      for (int jj = 0; jj < 4; ++jj) {
        int idx = w * 4 + jj, sc = idx >> 2, kt = idx & 3;
        int s = sb + ci * 4 + sc;
        int t = dir ? (TT - 1 - s) : s;
        gl_lds16(x + ((size_t)(b0p + lq) * TT + t) * 128 + kt * 32 + lg * 8,
                 xr + buf * 8192 + sc * 2048 + kt * 512);
      }
    };

    stage(0);
    for (int ci = 0; ci < 4; ++ci) {
      __syncthreads();   // drains this wave's gl_lds (vmcnt0) + fences + barrier
      if (ci < 3) stage(ci + 1);
      int buf = ci & 1;
      #pragma unroll
      for (int sc = 0; sc < 4; ++sc) {
        int s = sb + ci * 4 + sc;
        bf16x8 xf[4];
        #pragma unroll
        for (int kt = 0; kt < 4; ++kt)
          xf[kt] = *reinterpret_cast<const bf16x8*>(xr + buf * 8192 + sc * 2048 + kt * 512 + l * 8);
        f32x4 acc[4][2];
        #pragma unroll
        for (int g = 0; g < 4; ++g)
          #pragma unroll
          for (int j = 0; j < 2; ++j)
            acc[g][j] = f32x4{bs[g][j], bs[g][j], bs[g][j], bs[g][j]};
        #pragma unroll
        for (int kt = 0; kt < 4; ++kt)
          #pragma unroll
          for (int g = 0; g < 4; ++g) {
            acc[g][0] = __builtin_amdgcn_mfma_f32_16x16x32_bf16(xf[kt], wx[g][0][kt], acc[g][0], 0, 0, 0);
            acc[g][1] = __builtin_amdgcn_mfma_f32_16x16x32_bf16(xf[kt], wx[g][1][kt], acc[g][1], 0, 0, 0);
          }
        // write in consumer record order
        float* zp = zprod + (size_t)(s - zs0) * 262144 +
                    ((size_t)((dir * 32 + rg2 * 2 + (lg >> 1)) * 4 + w)) * 1024 +
                    ((lg & 1) * 16 + lq) * 32;
        #pragma unroll
        for (int g = 0; g < 4; ++g)
          #pragma unroll
          for (int j = 0; j < 2; ++j)
            *reinterpret_cast<f32x4*>(zp + g * 8 + j * 4) = acc[g][j];
      }
    }
  }
}

// ---------------- logits = [h_f, h_b] @ Wd + bd via MFMA ----------------
__global__ __launch_bounds__(256) void k_logits(const unsigned short* __restrict__ hseq,
                                                const unsigned short* __restrict__ WdT,
                                                const float* __restrict__ bd,
                                                float* __restrict__ logits) {
  __shared__ __align__(16) unsigned short xt[2][16384];  // 2 x 32KB
  const int tid = threadIdx.x, wv = tid >> 6, l = tid & 63;
  const int lq = l & 15, lg = l >> 4;
  const size_t HS = (size_t)BB * TT * 128;

  bf16x8 wb[8];
  #pragma unroll
  for (int kt = 0; kt < 8; ++kt)
    wb[kt] = *reinterpret_cast<const bf16x8*>(WdT + lq * 256 + kt * 32 + lg * 8);
  float bdv = (lq < TAGS) ? bd[lq] : 0.f;

  auto stage = [&](int it, int buf) {
    int bt0 = blockIdx.x * 256 + it * 64;
    #pragma unroll
    for (int i = 0; i < 8; ++i) {
      int v = tid + i * 256;                 // lds unit
      int g = v ^ ((v >> 5) & 7);            // pre-swizzled source unit
      int row = g >> 5, cu = g & 31;
      const unsigned short* src = (cu < 16)
          ? hseq + (size_t)(bt0 + row) * 128 + cu * 8
          : hseq + HS + (size_t)(bt0 + row) * 128 + (cu - 16) * 8;
      gl_lds16(src, &xt[buf][(i * 256 + wv * 64) * 8]);
    }
  };

  stage(0, 0);
  for (int it = 0; it < 4; ++it) {
    __syncthreads();   // drains gl_lds (vmcnt0 per wave) + barrier: tile `it` ready
    if (it < 3) stage(it + 1, (it + 1) & 1);
    int buf = it & 1;
    int bt0 = blockIdx.x * 256 + it * 64;
    int r0 = wv * 16;
    bf16x8 af[8];
    #pragma unroll
    for (int kt = 0; kt < 8; ++kt) {
      int u = (r0 + lq) * 32 + kt * 4 + lg;
      af[kt] = *reinterpret_cast<const bf16x8*>(&xt[buf][(u ^ ((u >> 5) & 7)) * 8]);
    }
    f32x4 acc = f32x4{bdv, bdv, bdv, bdv};
    #pragma unroll
    for (int kt = 0; kt < 8; ++kt)
      acc = __builtin_amdgcn_mfma_f32_16x16x32_bf16(af[kt], wb[kt], acc, 0, 0, 0);
    if (lq < TAGS) {
      #pragma unroll
      for (int r = 0; r < 4; ++r)
        logits[(size_t)(bt0 + r0 + lg * 4 + r) * TAGS + lq] = acc[r];
    }
  }
}

// ---------------- CRF log-likelihood; one wave per batch row ----------------
__global__ void k_crf(const float* __restrict__ logits, const int* __restrict__ labels,
                      const int* __restrict__ lengths, const float* __restrict__ trans,
                      float* __restrict__ out) {
  int b = blockIdx.x;
  int lane = threadIdx.x;
  int len = lengths[b];
  const float* lg = logits + (size_t)b * TT * TAGS;
  const int*   lab = labels + b * TT;

  float sc = 0.f;
  for (int t = lane; t < TT; t += 64) {
    if (t < len) {
      sc += lg[t * TAGS + lab[t]];
      if (t >= 1) sc += trans[lab[t - 1] * TAGS + lab[t]];
    }
  }
  for (int o = 32; o > 0; o >>= 1) sc += __shfl_down(sc, o);
  sc = __shfl(sc, 0);

  int j = (lane < TAGS) ? lane : 0;
  float Tc[TAGS];
  #pragma unroll
  for (int i = 0; i < TAGS; ++i) Tc[i] = trans[i * TAGS + j];
  float alpha[TAGS];
  #pragma unroll
  for (int i = 0; i < TAGS; ++i) alpha[i] = lg[i];

  float pre[8];
  #pragma unroll
  for (int k = 0; k < 8; ++k) pre[k] = (1 + k < TT) ? lg[(1 + k) * TAGS + j] : 0.f;

  for (int tb = 1; tb < TT; tb += 8) {
    #pragma unroll
    for (int u = 0; u < 8; ++u) {
      int t = tb + u;
      if (t < TT) {
        float m = -1e30f;
        #pragma unroll
        for (int i = 0; i < TAGS; ++i) m = fmaxf(m, alpha[i] + Tc[i]);
        float ssum = 0.f;
        #pragma unroll
        for (int i = 0; i < TAGS; ++i) ssum += __expf(alpha[i] + Tc[i] - m);
        float nj = m + __logf(ssum) + pre[u];
        int tf = t + 8;
        pre[u] = (tf < TT) ? lg[tf * TAGS + j] : 0.f;
        bool upd = (t < len);
        float na[TAGS];
        #pragma unroll
        for (int i = 0; i < TAGS; ++i) na[i] = __shfl(nj, i);
        if (upd)
          #pragma unroll
          for (int i = 0; i < TAGS; ++i) alpha[i] = na[i];
      }
    }
  }
  if (lane == 0) {
    float m = -1e30f;
    #pragma unroll
    for (int i = 0; i < TAGS; ++i) m = fmaxf(m, alpha[i]);
    float ssum = 0.f;
    #pragma unroll
    for (int i = 0; i < TAGS; ++i) ssum += __expf(alpha[i] - m);
    float ln = m + __logf(ssum);
    out[b] = (len > 0) ? (sc - ln) : 0.f;
  }
}

__global__ void k_copy_trans(const float* __restrict__ trans, float* __restrict__ out) {
  int i = threadIdx.x;
  if (i < TAGS * TAGS) out[BB + i] = trans[i];
}

extern "C" void kernel_launch(void* const* d_in, const int* in_sizes, int n_in,
                              void* d_out, int out_size, void* d_ws, size_t ws_size,
                              hipStream_t stream) {
  const int*   inp    = (const int*)d_in[0];
  const float* ch     = (const float*)d_in[1];
  const int*   labels = (const int*)d_in[2];
  const float* E      = (const float*)d_in[3];
  const float* Wx_f   = (const float*)d_in[4];
  const float* Wh_f   = (const float*)d_in[5];
  const float* b_f    = (const float*)d_in[6];
  const float* Wx_b   = (const float*)d_in[7];
  const float* Wh_b   = (const float*)d_in[8];
  const float* b_b    = (const float*)d_in[9];
  const float* Wd     = (const float*)d_in[10];
  const float* bd     = (const float*)d_in[11];
  const float* trans  = (const float*)d_in[12];
  float* out = (float*)d_out;

  // workspace layout (all 16B aligned)
  unsigned short* x    = (unsigned short*)d_ws;                 // 33.55 MB
  unsigned short* hseq = x + (size_t)BB * TT * 128;             // 67.11 MB
  unsigned short* WxT  = hseq + (size_t)2 * BB * TT * 128;      // 0.26 MB
  unsigned short* WhT  = WxT + 2 * NG * 128;                    // 0.26 MB
  unsigned short* WdT  = WhT + 2 * NG * 128;                    // 8 KB
  float* logits        = (float*)(WdT + 16 * 256);              // 4.72 MB
  float* cbuf          = logits + (size_t)BB * TT * TAGS;       // 0.26 MB
  int*   lengths       = (int*)(cbuf + (size_t)2 * BB * RNN);   // 1 KB
  float* zbuf          = (float*)(lengths + 256);               // 2 * L MB (f32)

  const size_t fixed_b = 106439680ull;
  int NP = 8;
  if (fixed_b + 2ull * (TT / 8)  * 1048576ull > ws_size) NP = 16;
  if (fixed_b + 2ull * (TT / 16) * 1048576ull > ws_size) NP = 32;
  const int L = TT / NP;
  const size_t zsl = (size_t)L * 262144;  // f32 elements per slice

  k_build_x<<<(BB * TT * 128) / 256, 256, 0, stream>>>(inp, ch, E, x);
  k_prep_w<<<513, 256, 0, stream>>>(Wx_f, Wh_f, Wx_b, Wh_b, Wd, WxT, WhT, WdT);
  k_lengths<<<BB, 64, 0, stream>>>(labels, lengths);

  // initial zgemm for pass 0 (no lstm blocks)
  k_fused<<<2 * L, 256, 0, stream>>>(x, WxT, WhT, b_f, b_b,
                                     zbuf, zbuf, hseq, cbuf,
                                     0, 0, 0, 1, 0, L);
  for (int p = 0; p < NP; ++p) {
    int nz = (p + 1 < NP) ? 2 * L : 0;
    k_fused<<<64 + nz, 256, 0, stream>>>(
        x, WxT, WhT, b_f, b_b,
        zbuf + (size_t)(p & 1) * zsl,         // consumer slice
        zbuf + (size_t)((p + 1) & 1) * zsl,   // producer slice
        hseq, cbuf,
        64, p * L, (p + 1) * L, (p == 0) ? 1 : 0, (p + 1) * L, nz ? L : 0);
  }

  k_logits<<<(BB * TT) / 256, 256, 0, stream>>>(hseq, WdT, bd, logits);
  k_crf<<<BB, 64, 0, stream>>>(logits, labels, lengths, trans, out);
  k_copy_trans<<<1, 128, 0, stream>>>(trans, out);
}

// Round 6
// 736.822 us; speedup vs baseline: 1.2623x; 1.2623x over previous
//
#include <hip/hip_runtime.h>

#define BB   256
#define TT   512
#define EMBD 64
#define CHARD 50
#define DIN  114
#define RNN  128
#define NG   512   // 4*RNN
#define TAGS 9

typedef __bf16 bf16x8 __attribute__((ext_vector_type(8)));
typedef float  f32x4  __attribute__((ext_vector_type(4)));

static __device__ __forceinline__ unsigned short f2bf(float f) {
  unsigned int u = __float_as_uint(f);
  unsigned int r = (u + 0x7FFFu + ((u >> 16) & 1u)) >> 16;  // RNE
  return (unsigned short)r;
}
static __device__ __forceinline__ void gl_lds16(const void* g, void* l) {
  __builtin_amdgcn_global_load_lds(
      (const __attribute__((address_space(1))) unsigned int*)g,
      (__attribute__((address_space(3))) unsigned int*)l, 16, 0, 0);
}

// ---------------- x = concat(E[inputs], char_emb) padded to 128, bf16 ----------------
__global__ void k_build_x(const int* __restrict__ inp, const float* __restrict__ ch,
                          const float* __restrict__ E, unsigned short* __restrict__ x) {
  int idx = blockIdx.x * 256 + threadIdx.x;
  int k   = idx & 127;
  int row = idx >> 7;
  float v;
  if (k < EMBD)      v = E[inp[row] * EMBD + k];
  else if (k < DIN)  v = ch[row * CHARD + (k - EMBD)];
  else               v = 0.f;
  x[idx] = f2bf(v);
}

// ------- weights -> [n][k] bf16; block 512 builds WdT [16][256] -------
__global__ void k_prep_w(const float* __restrict__ Wx_f, const float* __restrict__ Wh_f,
                         const float* __restrict__ Wx_b, const float* __restrict__ Wh_b,
                         const float* __restrict__ Wd,
                         unsigned short* __restrict__ WxT, unsigned short* __restrict__ WhT,
                         unsigned short* __restrict__ WdT) {
  if (blockIdx.x == 512) {
    for (int i = threadIdx.x; i < 16 * 256; i += 256) {
      int n = i >> 8, k = i & 255;
      WdT[i] = (n < TAGS) ? f2bf(Wd[k * TAGS + n]) : (unsigned short)0;
    }
    return;
  }
  int idx = blockIdx.x * 256 + threadIdx.x;
  int dir = idx >> 16;
  int rem = idx & 65535;
  int n   = rem >> 7;
  int kk  = rem & 127;
  const float* Wx = dir ? Wx_b : Wx_f;
  const float* Wh = dir ? Wh_b : Wh_f;
  WxT[idx] = (kk < DIN) ? f2bf(Wx[kk * NG + n]) : (unsigned short)0;
  WhT[idx] = f2bf(Wh[kk * NG + n]);
}

__global__ void k_lengths(const int* __restrict__ labels, int* __restrict__ lengths) {
  int b = blockIdx.x, lane = threadIdx.x;
  int cnt = 0;
  for (int t = lane; t < TT; t += 64) cnt += (labels[b * TT + t] != 0);
  for (int o = 32; o > 0; o >>= 1) cnt += __shfl_down(cnt, o);
  if (lane == 0) lengths[b] = cnt;
}

// ==================== fused per-pass kernel (512 threads) ====================
// Blocks [0,lstm_n): LSTM, 8 rows per block, 8 waves (wave w = hidden slice
//   w*16..w*16+16, 16 MFMA/step). h ring in swizzled LDS. z (f32, bias incl.)
//   loaded straight into accumulators, record layout [dir][rg][w][lg][g][lq][r].
//   Inner barrier = lgkmcnt-only + sched_barrier fences (no vmcnt drain).
// Blocks [lstm_n,...): z = x@Wx + b producer for the NEXT pass (16-row tiles).
__global__ __launch_bounds__(512, 2) void k_fused(
    const unsigned short* __restrict__ x,
    const unsigned short* __restrict__ WxT,
    const unsigned short* __restrict__ WhT,
    const float* __restrict__ b_f, const float* __restrict__ b_b,
    const float* __restrict__ zcons, float* __restrict__ zprod,
    unsigned short* __restrict__ hseq, float* __restrict__ cbuf,
    int lstm_n, int s0, int s1, int first, int zs0, int znsteps)
{
  __shared__ __align__(16) char LDS[32768];
  const int tid = threadIdx.x, w = tid >> 6, l = tid & 63;
  const int lq = l & 15, lg = l >> 4;

  if ((int)blockIdx.x < lstm_n) {
    // ---------------- LSTM consumer ----------------
    const int wg = blockIdx.x, dir = wg >> 5, rg = wg & 31, b0 = rg * 8;
    const unsigned short* WhD = WhT + dir * (NG * 128);
    unsigned short* hout = hseq + (size_t)dir * ((size_t)BB * TT * 128);
    char* ring = LDS;  // 8 slots x 2048 B (8 rows x 128 bf16, unit ^= row)

    // Wh B-frags: n = g*128 + w*16 + lq, k = kt*32 + lg*8
    bf16x8 wh[4][4];
    #pragma unroll
    for (int g = 0; g < 4; ++g)
      #pragma unroll
      for (int kt = 0; kt < 4; ++kt)
        wh[g][kt] = *reinterpret_cast<const bf16x8*>(
            WhD + (g * RNN + w * 16 + lq) * 128 + kt * 32 + lg * 8);

    // A-frag read offsets (bytes in slot): row = l&7 mirrored
    const int row7 = l & 7;
    int ro[4];
    #pragma unroll
    for (int kt = 0; kt < 4; ++kt)
      ro[kt] = (row7 * 16 + (((kt * 4) + lg) ^ row7)) * 16;

    // gate mapping: lane handles rows rowr(rr)= (lg&1)*4 + (lg>>1)*2 + rr, rr=0,1
    // at hidden = w*16 + lq
    int wo[2], rowr[2];
    #pragma unroll
    for (int rr = 0; rr < 2; ++rr) {
      rowr[rr] = (lg & 1) * 4 + (lg >> 1) * 2 + rr;
      int unit = rowr[rr] * 16 + ((w * 2 + (lq >> 3)) ^ rowr[rr]);
      wo[rr] = unit * 16 + (lq & 7) * 2;
    }
    const int hidden = w * 16 + lq;

    // restore h(s0-1) into slot 7; c from cbuf (or zeros)
    if (tid < 128) {
      int row = tid >> 4, h16 = tid & 15;
      int unit = row * 16 + (h16 ^ row);
      if (first) {
        *reinterpret_cast<f32x4*>(ring + 7 * 2048 + unit * 16) = f32x4{0.f, 0.f, 0.f, 0.f};
      } else {
        int tprev = dir ? (TT - s0) : (s0 - 1);
        bf16x8 v = *reinterpret_cast<const bf16x8*>(
            hout + ((size_t)(b0 + row) * TT + tprev) * 128 + h16 * 8);
        *reinterpret_cast<bf16x8*>(ring + 7 * 2048 + unit * 16) = v;
      }
    }
    float c[2];
    #pragma unroll
    for (int rr = 0; rr < 2; ++rr)
      c[rr] = first ? 0.f : cbuf[(size_t)(dir * BB + b0 + rowr[rr]) * RNN + hidden];
    __syncthreads();

    // z records: rec = ((dir*32+rg)*8 + w)*2 + lg (lg<2 valid), dims [g][lq][r]
    const float* zQ = zcons + (size_t)(((dir * 32 + rg) * 8 + w) * 2 + (lg & 1)) * 256;
    f32x4 zc[4];
    if (lg < 2) {
      #pragma unroll
      for (int g = 0; g < 4; ++g)
        zc[g] = *reinterpret_cast<const f32x4*>(zQ + g * 64 + lq * 4);
    }

    auto gather = [&](int sp) {  // store 4 steps of h, coalesced
      int h16 = tid & 15, tc = (tid >> 4) & 3, row = tid >> 6;
      int ss = sp + tc, t = dir ? (TT - 1 - ss) : ss;
      bf16x8 v = *reinterpret_cast<const bf16x8*>(
          ring + (ss & 7) * 2048 + (row * 16 + (h16 ^ row)) * 16);
      *reinterpret_cast<bf16x8*>(hout + ((size_t)(b0 + row) * TT + t) * 128 + h16 * 8) = v;
    };

    for (int s = s0; s < s1; ++s) {
      f32x4 acc[4];
      #pragma unroll
      for (int g = 0; g < 4; ++g)
        acc[g] = (lg < 2) ? zc[g] : f32x4{0.f, 0.f, 0.f, 0.f};
      // prefetch next step's z (stays in flight across the lgkm-only barrier)
      {
        int sn = (s + 1 < s1) ? (s + 1) : (s1 - 1);
        if (lg < 2) {
          const float* zp = zQ + (size_t)(sn - s0) * 262144;
          #pragma unroll
          for (int g = 0; g < 4; ++g)
            zc[g] = *reinterpret_cast<const f32x4*>(zp + g * 64 + lq * 4);
        }
      }

      const char* rb = ring + ((s - 1) & 7) * 2048;
      bf16x8 hf[4];
      #pragma unroll
      for (int kt = 0; kt < 4; ++kt)
        hf[kt] = *reinterpret_cast<const bf16x8*>(rb + ro[kt]);
      #pragma unroll
      for (int kt = 0; kt < 4; ++kt)
        #pragma unroll
        for (int g = 0; g < 4; ++g)
          acc[g] = __builtin_amdgcn_mfma_f32_16x16x32_bf16(hf[kt], wh[g][kt], acc[g], 0, 0, 0);

      if ((s & 3) == 0 && s > s0) gather(s - 4);

      // pack: lanes>=32 receive r=2,3 values of lanes<32
      float sw_[4][2];
      #pragma unroll
      for (int g = 0; g < 4; ++g)
        #pragma unroll
        for (int rr = 0; rr < 2; ++rr) {
          float d = acc[g][2 + rr], sv = acc[g][2 + rr];
          asm volatile("v_permlane32_swap_b32 %0, %1" : "+v"(d), "+v"(sv));
          sw_[g][rr] = d;
        }

      char* wslot = ring + (s & 7) * 2048;
      #pragma unroll
      for (int rr = 0; rr < 2; ++rr) {
        float zi = (lg < 2) ? acc[0][rr] : sw_[0][rr];
        float zf = (lg < 2) ? acc[1][rr] : sw_[1][rr];
        float zg = (lg < 2) ? acc[2][rr] : sw_[2][rr];
        float zo = (lg < 2) ? acc[3][rr] : sw_[3][rr];
        zi = fminf(20.f, fmaxf(-20.f, zi));
        zf = fminf(20.f, fmaxf(-20.f, zf));
        zg = fminf(20.f, fmaxf(-20.f, zg));
        zo = fminf(20.f, fmaxf(-20.f, zo));
        float ei = __expf(-zi), ef = __expf(-zf), eo = __expf(-zo);
        float g2 = __expf(2.f * zg);
        float P   = (1.f + ei) * (g2 + 1.f);
        float efp = 1.f + ef;
        float cn  = (c[rr] * P + efp * (g2 - 1.f)) * __builtin_amdgcn_rcpf(efp * P);
        c[rr] = cn;
        float cc = fminf(20.f, fmaxf(-20.f, cn));
        float ec = __expf(2.f * cc);
        float hn = (ec - 1.f) * __builtin_amdgcn_rcpf((1.f + eo) * (ec + 1.f));
        *reinterpret_cast<unsigned short*>(wslot + wo[rr]) = f2bf(hn);
      }
      __builtin_amdgcn_sched_barrier(0);
      asm volatile("s_waitcnt lgkmcnt(0)" ::: "memory");
      __builtin_amdgcn_s_barrier();
      __builtin_amdgcn_sched_barrier(0);
    }

    gather(s1 - 4);
    #pragma unroll
    for (int rr = 0; rr < 2; ++rr)
      cbuf[(size_t)(dir * BB + b0 + rowr[rr]) * RNN + hidden] = c[rr];
  } else {
    // ---------------- zgemm producer (next pass), 16-row tiles ----------------
    if (znsteps <= 0) return;
    const int TCHN = znsteps >> 4;
    const int zb = blockIdx.x - lstm_n;
    const int per = 16 * TCHN;
    const int dir = zb / per;
    const int rem = zb % per;
    const int rg2 = rem / TCHN, tch = rem % TCHN;
    const int b0p = rg2 * 16;
    const int sb  = zs0 + tch * 16;

    const unsigned short* WxD = WxT + dir * (NG * 128);
    const float* bias = dir ? b_b : b_f;
    unsigned short* xr = (unsigned short*)LDS;  // [2 buf][4 sc][4 kt][64 l][8]

    bf16x8 wx[4][4];
    float  bs[4];
    #pragma unroll
    for (int g = 0; g < 4; ++g) {
      int n = g * RNN + w * 16 + lq;
      bs[g] = bias[n];
      #pragma unroll
      for (int kt = 0; kt < 4; ++kt)
        wx[g][kt] = *reinterpret_cast<const bf16x8*>(WxD + n * 128 + kt * 32 + lg * 8);
    }

    auto stage = [&](int ci) {
      int buf = ci & 1;
      #pragma unroll
      for (int jj = 0; jj < 2; ++jj) {
        int idx = w * 2 + jj, sc = idx >> 2, kt = idx & 3;
        int s = sb + ci * 4 + sc;
        int t = dir ? (TT - 1 - s) : s;
        gl_lds16(x + ((size_t)(b0p + lq) * TT + t) * 128 + kt * 32 + lg * 8,
                 xr + buf * 8192 + sc * 2048 + kt * 512);
      }
    };

    stage(0);
    for (int ci = 0; ci < 4; ++ci) {
      __syncthreads();   // drains gl_lds + fences
      if (ci < 3) stage(ci + 1);
      int buf = ci & 1;
      #pragma unroll
      for (int sc = 0; sc < 4; ++sc) {
        int s = sb + ci * 4 + sc;
        bf16x8 xf[4];
        #pragma unroll
        for (int kt = 0; kt < 4; ++kt)
          xf[kt] = *reinterpret_cast<const bf16x8*>(xr + buf * 8192 + sc * 2048 + kt * 512 + l * 8);
        f32x4 acc[4];
        #pragma unroll
        for (int g = 0; g < 4; ++g) acc[g] = f32x4{bs[g], bs[g], bs[g], bs[g]};
        #pragma unroll
        for (int kt = 0; kt < 4; ++kt)
          #pragma unroll
          for (int g = 0; g < 4; ++g)
            acc[g] = __builtin_amdgcn_mfma_f32_16x16x32_bf16(xf[kt], wx[g][kt], acc[g], 0, 0, 0);
        // consumer record order: rec = ((dir*32 + rg2*2+(lg>=2))*8 + w)*2 + (lg&1)
        float* zp = zprod + (size_t)(s - zs0) * 262144 +
                    (size_t)(((dir * 32 + rg2 * 2 + (lg >> 1)) * 8 + w) * 2 + (lg & 1)) * 256 +
                    lq * 4;
        #pragma unroll
        for (int g = 0; g < 4; ++g)
          *reinterpret_cast<f32x4*>(zp + g * 64) = acc[g];
      }
    }
  }
}

// ---------------- logits + EUK = exp(logit - rowmax), rowmax ----------------
__global__ __launch_bounds__(256) void k_logits(const unsigned short* __restrict__ hseq,
                                                const unsigned short* __restrict__ WdT,
                                                const float* __restrict__ bd,
                                                float* __restrict__ logits,
                                                float* __restrict__ euk) {
  __shared__ __align__(16) unsigned short xt[2][16384];
  const int tid = threadIdx.x, wv = tid >> 6, l = tid & 63;
  const int lq = l & 15, lg = l >> 4;
  const size_t HS = (size_t)BB * TT * 128;

  bf16x8 wb[8];
  #pragma unroll
  for (int kt = 0; kt < 8; ++kt)
    wb[kt] = *reinterpret_cast<const bf16x8*>(WdT + lq * 256 + kt * 32 + lg * 8);
  float bdv = (lq < TAGS) ? bd[lq] : 0.f;

  auto stage = [&](int it, int buf) {
    int bt0 = blockIdx.x * 256 + it * 64;
    #pragma unroll
    for (int i = 0; i < 8; ++i) {
      int v = tid + i * 256;
      int g = v ^ ((v >> 5) & 7);
      int row = g >> 5, cu = g & 31;
      const unsigned short* src = (cu < 16)
          ? hseq + (size_t)(bt0 + row) * 128 + cu * 8
          : hseq + HS + (size_t)(bt0 + row) * 128 + (cu - 16) * 8;
      gl_lds16(src, &xt[buf][(i * 256 + wv * 64) * 8]);
    }
  };

  stage(0, 0);
  for (int it = 0; it < 4; ++it) {
    __syncthreads();
    if (it < 3) stage(it + 1, (it + 1) & 1);
    int buf = it & 1;
    int bt0 = blockIdx.x * 256 + it * 64;
    int r0 = wv * 16;
    bf16x8 af[8];
    #pragma unroll
    for (int kt = 0; kt < 8; ++kt) {
      int u = (r0 + lq) * 32 + kt * 4 + lg;
      af[kt] = *reinterpret_cast<const bf16x8*>(&xt[buf][(u ^ ((u >> 5) & 7)) * 8]);
    }
    f32x4 acc = f32x4{bdv, bdv, bdv, bdv};
    #pragma unroll
    for (int kt = 0; kt < 8; ++kt)
      acc = __builtin_amdgcn_mfma_f32_16x16x32_bf16(af[kt], wb[kt], acc, 0, 0, 0);
    // row max over j (lanes lq 0..8 within 16-lane group)
    float mr[4];
    #pragma unroll
    for (int r = 0; r < 4; ++r) {
      float v = (lq < TAGS) ? acc[r] : -1e30f;
      #pragma unroll
      for (int o = 1; o < 16; o <<= 1) v = fmaxf(v, __shfl_xor(v, o, 16));
      mr[r] = v;
    }
    #pragma unroll
    for (int r = 0; r < 4; ++r) {
      int rowi = bt0 + r0 + lg * 4 + r;
      if (lq < TAGS) logits[(size_t)rowi * TAGS + lq] = acc[r];
      if (lq < 12) {
        float val = (lq < TAGS) ? __expf(acc[r] - mr[r]) : ((lq == TAGS) ? mr[r] : 0.f);
        euk[(size_t)rowi * 12 + lq] = val;
      }
    }
  }
}

// ---------------- unary+binary sequence score; one wave per row ----------------
__global__ void k_score(const float* __restrict__ logits, const int* __restrict__ labels,
                        const int* __restrict__ lengths, const float* __restrict__ trans,
                        float* __restrict__ scbuf) {
  int b = blockIdx.x, lane = threadIdx.x;
  int len = lengths[b];
  const float* lg = logits + (size_t)b * TT * TAGS;
  const int*   lab = labels + b * TT;
  float sc = 0.f;
  for (int t = lane; t < TT; t += 64) {
    if (t < len) {
      sc += lg[t * TAGS + lab[t]];
      if (t >= 1) sc += trans[lab[t - 1] * TAGS + lab[t]];
    }
  }
  for (int o = 32; o > 0; o >>= 1) sc += __shfl_down(sc, o);
  if (lane == 0) scbuf[b] = sc;
}

// ------- CRF forward recursion in exp-space: 1 row/lane, 64 rows/wave -------
// a_new[j] = (sum_i a[i]*exp(T[i][j])) * EU[t][j]; exact pow2 rescale each step.
__global__ __launch_bounds__(64) void k_crf2(const float* __restrict__ euk,
                                             const float* __restrict__ scbuf,
                                             const int* __restrict__ lengths,
                                             const float* __restrict__ trans,
                                             float* __restrict__ out) {
  int b = blockIdx.x * 64 + threadIdx.x;
  float Et[81];
  #pragma unroll
  for (int i = 0; i < 81; ++i) Et[i] = __expf(trans[i]);
  const float* ep = euk + (size_t)b * TT * 12;
  int len = lengths[b];

  float4 e0 = *reinterpret_cast<const float4*>(ep);
  float4 e1 = *reinterpret_cast<const float4*>(ep + 4);
  float4 e2 = *reinterpret_cast<const float4*>(ep + 8);
  float a[9] = {e0.x, e0.y, e0.z, e0.w, e1.x, e1.y, e1.z, e1.w, e2.x};
  float Ks = e2.y;
  int E2 = 0;
  float4 f0 = *reinterpret_cast<const float4*>(ep + 12);
  float4 f1 = *reinterpret_cast<const float4*>(ep + 16);
  float4 f2 = *reinterpret_cast<const float4*>(ep + 20);

  for (int t = 1; t < TT; ++t) {
    float eu[9] = {f0.x, f0.y, f0.z, f0.w, f1.x, f1.y, f1.z, f1.w, f2.x};
    float mt = f2.y;
    if (t + 1 < TT) {
      const float* np = ep + (size_t)(t + 1) * 12;
      f0 = *reinterpret_cast<const float4*>(np);
      f1 = *reinterpret_cast<const float4*>(np + 4);
      f2 = *reinterpret_cast<const float4*>(np + 8);
    }
    bool upd = (t < len);
    float an[9];
    #pragma unroll
    for (int j = 0; j < 9; ++j) {
      float s = a[0] * Et[j];
      #pragma unroll
      for (int i = 1; i < 9; ++i) s = fmaf(a[i], Et[i * 9 + j], s);
      an[j] = s * eu[j];
    }
    #pragma unroll
    for (int j = 0; j < 9; ++j) a[j] = upd ? an[j] : a[j];
    Ks += upd ? mt : 0.f;
    // exact pow2 renorm
    float s = fmaxf(fmaxf(fmaxf(a[0], a[1]), fmaxf(a[2], a[3])),
                    fmaxf(fmaxf(a[4], a[5]), fmaxf(a[6], a[7])));
    s = fmaxf(s, a[8]);
    int e;
    frexpf(s, &e);
    E2 += e;
    #pragma unroll
    for (int j = 0; j < 9; ++j) a[j] = ldexpf(a[j], -e);
  }
  float S = ((a[0] + a[1]) + (a[2] + a[3])) + ((a[4] + a[5]) + (a[6] + a[7])) + a[8];
  float ln = logf(S) + (float)E2 * 0.69314718056f + Ks;
  out[b] = (len > 0) ? (scbuf[b] - ln) : 0.f;
}

__global__ void k_copy_trans(const float* __restrict__ trans, float* __restrict__ out) {
  int i = threadIdx.x;
  if (i < TAGS * TAGS) out[BB + i] = trans[i];
}

extern "C" void kernel_launch(void* const* d_in, const int* in_sizes, int n_in,
                              void* d_out, int out_size, void* d_ws, size_t ws_size,
                              hipStream_t stream) {
  const int*   inp    = (const int*)d_in[0];
  const float* ch     = (const float*)d_in[1];
  const int*   labels = (const int*)d_in[2];
  const float* E      = (const float*)d_in[3];
  const float* Wx_f   = (const float*)d_in[4];
  const float* Wh_f   = (const float*)d_in[5];
  const float* b_f    = (const float*)d_in[6];
  const float* Wx_b   = (const float*)d_in[7];
  const float* Wh_b   = (const float*)d_in[8];
  const float* b_b    = (const float*)d_in[9];
  const float* Wd     = (const float*)d_in[10];
  const float* bd     = (const float*)d_in[11];
  const float* trans  = (const float*)d_in[12];
  float* out = (float*)d_out;

  unsigned short* x    = (unsigned short*)d_ws;                 // 33.55 MB
  unsigned short* hseq = x + (size_t)BB * TT * 128;             // 67.11 MB
  unsigned short* WxT  = hseq + (size_t)2 * BB * TT * 128;      // 0.26 MB
  unsigned short* WhT  = WxT + 2 * NG * 128;                    // 0.26 MB
  unsigned short* WdT  = WhT + 2 * NG * 128;                    // 8 KB
  float* logits        = (float*)(WdT + 16 * 256);              // 4.72 MB
  float* euk           = logits + (size_t)BB * TT * TAGS;       // 6.29 MB
  float* cbuf          = euk + (size_t)BB * TT * 12;            // 0.26 MB
  float* scbuf         = cbuf + (size_t)2 * BB * RNN;           // 1 KB
  int*   lengths       = (int*)(scbuf + BB);                    // 1 KB
  float* zbuf          = (float*)(lengths + 256);

  const size_t zoff = (size_t)((char*)zbuf - (char*)d_ws);
  int NP = 8;
  if (zoff + 2ull * (TT / 8)  * 1048576ull > ws_size) NP = 16;
  if (zoff + 2ull * (TT / 16) * 1048576ull > ws_size) NP = 32;
  const int L = TT / NP;
  const size_t zsl = (size_t)L * 262144;  // f32 elements per slice

  k_build_x<<<(BB * TT * 128) / 256, 256, 0, stream>>>(inp, ch, E, x);
  k_prep_w<<<513, 256, 0, stream>>>(Wx_f, Wh_f, Wx_b, Wh_b, Wd, WxT, WhT, WdT);
  k_lengths<<<BB, 64, 0, stream>>>(labels, lengths);

  // prologue: produce z for pass 0
  k_fused<<<2 * 16 * (L / 16), 512, 0, stream>>>(x, WxT, WhT, b_f, b_b,
                                                 zbuf, zbuf, hseq, cbuf,
                                                 0, 0, 0, 1, 0, L);
  for (int p = 0; p < NP; ++p) {
    int nz = (p + 1 < NP) ? 2 * 16 * (L / 16) : 0;
    k_fused<<<64 + nz, 512, 0, stream>>>(
        x, WxT, WhT, b_f, b_b,
        zbuf + (size_t)(p & 1) * zsl,
        zbuf + (size_t)((p + 1) & 1) * zsl,
        hseq, cbuf,
        64, p * L, (p + 1) * L, (p == 0) ? 1 : 0, (p + 1) * L, nz ? L : 0);
  }

  k_logits<<<(BB * TT) / 256, 256, 0, stream>>>(hseq, WdT, bd, logits, euk);
  k_score<<<BB, 64, 0, stream>>>(logits, labels, lengths, trans, scbuf);
  k_crf2<<<BB / 64, 64, 0, stream>>>(euk, scbuf, lengths, trans, out);
  k_copy_trans<<<1, 128, 0, stream>>>(trans, out);
}

// Round 7
// 604.712 us; speedup vs baseline: 1.5381x; 1.2185x over previous
//
#include <hip/hip_runtime.h>

#define BB   256
#define TT   512
#define EMBD 64
#define CHARD 50
#define DIN  114
#define RNN  128
#define NG   512   // 4*RNN
#define TAGS 9

typedef __bf16 bf16x8 __attribute__((ext_vector_type(8)));
typedef float  f32x4  __attribute__((ext_vector_type(4)));
typedef unsigned int u32x2 __attribute__((ext_vector_type(2)));

static __device__ __forceinline__ unsigned short f2bf(float f) {
  unsigned int u = __float_as_uint(f);
  unsigned int r = (u + 0x7FFFu + ((u >> 16) & 1u)) >> 16;  // RNE
  return (unsigned short)r;
}
static __device__ __forceinline__ void gl_lds16(const void* g, void* l) {
  __builtin_amdgcn_global_load_lds(
      (const __attribute__((address_space(1))) unsigned int*)g,
      (__attribute__((address_space(3))) unsigned int*)l, 16, 0, 0);
}

// ---------------- x = concat(E[inputs], char_emb) padded to 128, bf16 ----------------
__global__ void k_build_x(const int* __restrict__ inp, const float* __restrict__ ch,
                          const float* __restrict__ E, unsigned short* __restrict__ x) {
  int idx = blockIdx.x * 256 + threadIdx.x;
  int k   = idx & 127;
  int row = idx >> 7;
  float v;
  if (k < EMBD)      v = E[inp[row] * EMBD + k];
  else if (k < DIN)  v = ch[row * CHARD + (k - EMBD)];
  else               v = 0.f;
  x[idx] = f2bf(v);
}

// ------- weights -> [n][k] bf16; block 512 builds WdT [16][256] -------
__global__ void k_prep_w(const float* __restrict__ Wx_f, const float* __restrict__ Wh_f,
                         const float* __restrict__ Wx_b, const float* __restrict__ Wh_b,
                         const float* __restrict__ Wd,
                         unsigned short* __restrict__ WxT, unsigned short* __restrict__ WhT,
                         unsigned short* __restrict__ WdT) {
  if (blockIdx.x == 512) {
    for (int i = threadIdx.x; i < 16 * 256; i += 256) {
      int n = i >> 8, k = i & 255;
      WdT[i] = (n < TAGS) ? f2bf(Wd[k * TAGS + n]) : (unsigned short)0;
    }
    return;
  }
  int idx = blockIdx.x * 256 + threadIdx.x;
  int dir = idx >> 16;
  int rem = idx & 65535;
  int n   = rem >> 7;
  int kk  = rem & 127;
  const float* Wx = dir ? Wx_b : Wx_f;
  const float* Wh = dir ? Wh_b : Wh_f;
  WxT[idx] = (kk < DIN) ? f2bf(Wx[kk * NG + n]) : (unsigned short)0;
  WhT[idx] = f2bf(Wh[kk * NG + n]);
}

__global__ void k_lengths(const int* __restrict__ labels, int* __restrict__ lengths) {
  int b = blockIdx.x, lane = threadIdx.x;
  int cnt = 0;
  for (int t = lane; t < TT; t += 64) cnt += (labels[b * TT + t] != 0);
  for (int o = 32; o > 0; o >>= 1) cnt += __shfl_down(cnt, o);
  if (lane == 0) lengths[b] = cnt;
}

// ==================== fused per-pass kernel (512 threads) ====================
// Blocks [0,lstm_n): LSTM, 8 rows, 8 waves; h ring in swizzled LDS; z (bf16,
//   bias incl.) depth-2 register-prefetched into accumulators.
// Blocks [lstm_n,...): z = x@Wx + b producer for the NEXT pass (bf16 records).
__global__ __launch_bounds__(512, 2) void k_fused(
    const unsigned short* __restrict__ x,
    const unsigned short* __restrict__ WxT,
    const unsigned short* __restrict__ WhT,
    const float* __restrict__ b_f, const float* __restrict__ b_b,
    const unsigned short* __restrict__ zcons, unsigned short* __restrict__ zprod,
    unsigned short* __restrict__ hseq, float* __restrict__ cbuf,
    int lstm_n, int s0, int s1, int first, int zs0, int znsteps)
{
  __shared__ __align__(16) char LDS[32768];
  const int tid = threadIdx.x, w = tid >> 6, l = tid & 63;
  const int lq = l & 15, lg = l >> 4;

  if ((int)blockIdx.x < lstm_n) {
    // ---------------- LSTM consumer ----------------
    const int wg = blockIdx.x, dir = wg >> 5, rg = wg & 31, b0 = rg * 8;
    const unsigned short* WhD = WhT + dir * (NG * 128);
    unsigned short* hout = hseq + (size_t)dir * ((size_t)BB * TT * 128);
    char* ring = LDS;  // 8 slots x 2048 B (8 rows x 128 bf16, unit ^= row)

    bf16x8 wh[4][4];
    #pragma unroll
    for (int g = 0; g < 4; ++g)
      #pragma unroll
      for (int kt = 0; kt < 4; ++kt)
        wh[g][kt] = *reinterpret_cast<const bf16x8*>(
            WhD + (g * RNN + w * 16 + lq) * 128 + kt * 32 + lg * 8);

    const int row7 = l & 7;
    int ro[4];
    #pragma unroll
    for (int kt = 0; kt < 4; ++kt)
      ro[kt] = (row7 * 16 + (((kt * 4) + lg) ^ row7)) * 16;

    int wo[2], rowr[2];
    #pragma unroll
    for (int rr = 0; rr < 2; ++rr) {
      rowr[rr] = (lg & 1) * 4 + (lg >> 1) * 2 + rr;
      int unit = rowr[rr] * 16 + ((w * 2 + (lq >> 3)) ^ rowr[rr]);
      wo[rr] = unit * 16 + (lq & 7) * 2;
    }
    const int hidden = w * 16 + lq;

    if (tid < 128) {
      int row = tid >> 4, h16 = tid & 15;
      int unit = row * 16 + (h16 ^ row);
      if (first) {
        *reinterpret_cast<f32x4*>(ring + 7 * 2048 + unit * 16) = f32x4{0.f, 0.f, 0.f, 0.f};
      } else {
        int tprev = dir ? (TT - s0) : (s0 - 1);
        bf16x8 v = *reinterpret_cast<const bf16x8*>(
            hout + ((size_t)(b0 + row) * TT + tprev) * 128 + h16 * 8);
        *reinterpret_cast<bf16x8*>(ring + 7 * 2048 + unit * 16) = v;
      }
    }
    float c[2];
    #pragma unroll
    for (int rr = 0; rr < 2; ++rr)
      c[rr] = first ? 0.f : cbuf[(size_t)(dir * BB + b0 + rowr[rr]) * RNN + hidden];
    __syncthreads();

    // z records (bf16): rec = ((dir*32+rg)*8 + w)*2 + (lg&1); dims [g][lq][r]
    const unsigned short* zQ = zcons +
        (size_t)(((dir * 32 + rg) * 8 + w) * 2 + (lg & 1)) * 256 + lq * 4;
    u32x2 zA[4], zB[4];
    if (lg < 2) {
      #pragma unroll
      for (int g = 0; g < 4; ++g) zA[g] = *reinterpret_cast<const u32x2*>(zQ + g * 64);
      const unsigned short* zp1 = zQ + (size_t)((s0 + 1 < s1) ? 1 : 0) * 262144;
      #pragma unroll
      for (int g = 0; g < 4; ++g) zB[g] = *reinterpret_cast<const u32x2*>(zp1 + g * 64);
    }

    auto gather = [&](int sp) {
      int h16 = tid & 15, tc = (tid >> 4) & 3, row = tid >> 6;
      int ss = sp + tc, t = dir ? (TT - 1 - ss) : ss;
      bf16x8 v = *reinterpret_cast<const bf16x8*>(
          ring + (ss & 7) * 2048 + (row * 16 + (h16 ^ row)) * 16);
      *reinterpret_cast<bf16x8*>(hout + ((size_t)(b0 + row) * TT + t) * 128 + h16 * 8) = v;
    };

    for (int s = s0; s < s1; ++s) {
      f32x4 acc[4];
      #pragma unroll
      for (int g = 0; g < 4; ++g) {
        unsigned int lo = zA[g][0], hi = zA[g][1];
        f32x4 zv = f32x4{__uint_as_float(lo << 16), __uint_as_float(lo & 0xffff0000u),
                         __uint_as_float(hi << 16), __uint_as_float(hi & 0xffff0000u)};
        acc[g] = (lg < 2) ? zv : f32x4{0.f, 0.f, 0.f, 0.f};
      }
      // rotate prefetch: zA <- zB, issue load for s+2
      {
        #pragma unroll
        for (int g = 0; g < 4; ++g) zA[g] = zB[g];
        int sn = (s + 2 < s1) ? (s + 2) : (s1 - 1);
        if (lg < 2) {
          const unsigned short* zp = zQ + (size_t)(sn - s0) * 262144;
          #pragma unroll
          for (int g = 0; g < 4; ++g) zB[g] = *reinterpret_cast<const u32x2*>(zp + g * 64);
        }
      }

      const char* rb = ring + ((s - 1) & 7) * 2048;
      bf16x8 hf[4];
      #pragma unroll
      for (int kt = 0; kt < 4; ++kt)
        hf[kt] = *reinterpret_cast<const bf16x8*>(rb + ro[kt]);
      #pragma unroll
      for (int kt = 0; kt < 4; ++kt)
        #pragma unroll
        for (int g = 0; g < 4; ++g)
          acc[g] = __builtin_amdgcn_mfma_f32_16x16x32_bf16(hf[kt], wh[g][kt], acc[g], 0, 0, 0);

      if ((s & 3) == 0 && s > s0) gather(s - 4);

      float sw_[4][2];
      #pragma unroll
      for (int g = 0; g < 4; ++g)
        #pragma unroll
        for (int rr = 0; rr < 2; ++rr) {
          float d = acc[g][2 + rr], sv = acc[g][2 + rr];
          asm volatile("v_permlane32_swap_b32 %0, %1" : "+v"(d), "+v"(sv));
          sw_[g][rr] = d;
        }

      char* wslot = ring + (s & 7) * 2048;
      #pragma unroll
      for (int rr = 0; rr < 2; ++rr) {
        float zi = (lg < 2) ? acc[0][rr] : sw_[0][rr];
        float zf = (lg < 2) ? acc[1][rr] : sw_[1][rr];
        float zg = (lg < 2) ? acc[2][rr] : sw_[2][rr];
        float zo = (lg < 2) ? acc[3][rr] : sw_[3][rr];
        zi = fminf(20.f, fmaxf(-20.f, zi));
        zf = fminf(20.f, fmaxf(-20.f, zf));
        zg = fminf(20.f, fmaxf(-20.f, zg));
        zo = fminf(20.f, fmaxf(-20.f, zo));
        float ei = __expf(-zi), ef = __expf(-zf), eo = __expf(-zo);
        float g2 = __expf(2.f * zg);
        float P   = (1.f + ei) * (g2 + 1.f);
        float efp = 1.f + ef;
        float cn  = (c[rr] * P + efp * (g2 - 1.f)) * __builtin_amdgcn_rcpf(efp * P);
        c[rr] = cn;
        float cc = fminf(20.f, fmaxf(-20.f, cn));
        float ec = __expf(2.f * cc);
        float hn = (ec - 1.f) * __builtin_amdgcn_rcpf((1.f + eo) * (ec + 1.f));
        *reinterpret_cast<unsigned short*>(wslot + wo[rr]) = f2bf(hn);
      }
      __builtin_amdgcn_sched_barrier(0);
      asm volatile("s_waitcnt lgkmcnt(0)" ::: "memory");
      __builtin_amdgcn_s_barrier();
      __builtin_amdgcn_sched_barrier(0);
    }

    gather(s1 - 4);
    #pragma unroll
    for (int rr = 0; rr < 2; ++rr)
      cbuf[(size_t)(dir * BB + b0 + rowr[rr]) * RNN + hidden] = c[rr];
  } else {
    // ---------------- zgemm producer (next pass), 16-row tiles ----------------
    if (znsteps <= 0) return;
    const int TCHN = znsteps >> 4;
    const int zb = blockIdx.x - lstm_n;
    const int per = 16 * TCHN;
    const int dir = zb / per;
    const int rem = zb % per;
    const int rg2 = rem / TCHN, tch = rem % TCHN;
    const int b0p = rg2 * 16;
    const int sb  = zs0 + tch * 16;

    const unsigned short* WxD = WxT + dir * (NG * 128);
    const float* bias = dir ? b_b : b_f;
    unsigned short* xr = (unsigned short*)LDS;

    bf16x8 wx[4][4];
    float  bs[4];
    #pragma unroll
    for (int g = 0; g < 4; ++g) {
      int n = g * RNN + w * 16 + lq;
      bs[g] = bias[n];
      #pragma unroll
      for (int kt = 0; kt < 4; ++kt)
        wx[g][kt] = *reinterpret_cast<const bf16x8*>(WxD + n * 128 + kt * 32 + lg * 8);
    }

    auto stage = [&](int ci) {
      int buf = ci & 1;
      #pragma unroll
      for (int jj = 0; jj < 2; ++jj) {
        int idx = w * 2 + jj, sc = idx >> 2, kt = idx & 3;
        int s = sb + ci * 4 + sc;
        int t = dir ? (TT - 1 - s) : s;
        gl_lds16(x + ((size_t)(b0p + lq) * TT + t) * 128 + kt * 32 + lg * 8,
                 xr + buf * 8192 + sc * 2048 + kt * 512);
      }
    };

    stage(0);
    for (int ci = 0; ci < 4; ++ci) {
      __syncthreads();
      if (ci < 3) stage(ci + 1);
      int buf = ci & 1;
      #pragma unroll
      for (int sc = 0; sc < 4; ++sc) {
        int s = sb + ci * 4 + sc;
        bf16x8 xf[4];
        #pragma unroll
        for (int kt = 0; kt < 4; ++kt)
          xf[kt] = *reinterpret_cast<const bf16x8*>(xr + buf * 8192 + sc * 2048 + kt * 512 + l * 8);
        f32x4 acc[4];
        #pragma unroll
        for (int g = 0; g < 4; ++g) acc[g] = f32x4{bs[g], bs[g], bs[g], bs[g]};
        #pragma unroll
        for (int kt = 0; kt < 4; ++kt)
          #pragma unroll
          for (int g = 0; g < 4; ++g)
            acc[g] = __builtin_amdgcn_mfma_f32_16x16x32_bf16(xf[kt], wx[g][kt], acc[g], 0, 0, 0);
        unsigned short* zp = zprod + (size_t)(s - zs0) * 262144 +
            (size_t)(((dir * 32 + rg2 * 2 + (lg >> 1)) * 8 + w) * 2 + (lg & 1)) * 256 + lq * 4;
        #pragma unroll
        for (int g = 0; g < 4; ++g) {
          ushort4 v;
          v.x = f2bf(acc[g][0]); v.y = f2bf(acc[g][1]);
          v.z = f2bf(acc[g][2]); v.w = f2bf(acc[g][3]);
          *reinterpret_cast<ushort4*>(zp + g * 64) = v;
        }
      }
    }
  }
}

// ---------------- logits + EUK = exp(logit - rowmax), rowmax ----------------
__global__ __launch_bounds__(256) void k_logits(const unsigned short* __restrict__ hseq,
                                                const unsigned short* __restrict__ WdT,
                                                const float* __restrict__ bd,
                                                float* __restrict__ logits,
                                                float* __restrict__ euk) {
  __shared__ __align__(16) unsigned short xt[2][16384];
  const int tid = threadIdx.x, wv = tid >> 6, l = tid & 63;
  const int lq = l & 15, lg = l >> 4;
  const size_t HS = (size_t)BB * TT * 128;

  bf16x8 wb[8];
  #pragma unroll
  for (int kt = 0; kt < 8; ++kt)
    wb[kt] = *reinterpret_cast<const bf16x8*>(WdT + lq * 256 + kt * 32 + lg * 8);
  float bdv = (lq < TAGS) ? bd[lq] : 0.f;

  auto stage = [&](int it, int buf) {
    int bt0 = blockIdx.x * 256 + it * 64;
    #pragma unroll
    for (int i = 0; i < 8; ++i) {
      int v = tid + i * 256;
      int g = v ^ ((v >> 5) & 7);
      int row = g >> 5, cu = g & 31;
      const unsigned short* src = (cu < 16)
          ? hseq + (size_t)(bt0 + row) * 128 + cu * 8
          : hseq + HS + (size_t)(bt0 + row) * 128 + (cu - 16) * 8;
      gl_lds16(src, &xt[buf][(i * 256 + wv * 64) * 8]);
    }
  };

  stage(0, 0);
  for (int it = 0; it < 4; ++it) {
    __syncthreads();
    if (it < 3) stage(it + 1, (it + 1) & 1);
    int buf = it & 1;
    int bt0 = blockIdx.x * 256 + it * 64;
    int r0 = wv * 16;
    bf16x8 af[8];
    #pragma unroll
    for (int kt = 0; kt < 8; ++kt) {
      int u = (r0 + lq) * 32 + kt * 4 + lg;
      af[kt] = *reinterpret_cast<const bf16x8*>(&xt[buf][(u ^ ((u >> 5) & 7)) * 8]);
    }
    f32x4 acc = f32x4{bdv, bdv, bdv, bdv};
    #pragma unroll
    for (int kt = 0; kt < 8; ++kt)
      acc = __builtin_amdgcn_mfma_f32_16x16x32_bf16(af[kt], wb[kt], acc, 0, 0, 0);
    float mr[4];
    #pragma unroll
    for (int r = 0; r < 4; ++r) {
      float v = (lq < TAGS) ? acc[r] : -1e30f;
      #pragma unroll
      for (int o = 1; o < 16; o <<= 1) v = fmaxf(v, __shfl_xor(v, o, 16));
      mr[r] = v;
    }
    #pragma unroll
    for (int r = 0; r < 4; ++r) {
      int rowi = bt0 + r0 + lg * 4 + r;
      if (lq < TAGS) logits[(size_t)rowi * TAGS + lq] = acc[r];
      if (lq < 12) {
        float val = (lq < TAGS) ? __expf(acc[r] - mr[r]) : ((lq == TAGS) ? mr[r] : 0.f);
        euk[(size_t)rowi * 12 + lq] = val;
      }
    }
  }
}

// ---------------- unary+binary sequence score; one wave per row ----------------
__global__ void k_score(const float* __restrict__ logits, const int* __restrict__ labels,
                        const int* __restrict__ lengths, const float* __restrict__ trans,
                        float* __restrict__ scbuf) {
  int b = blockIdx.x, lane = threadIdx.x;
  int len = lengths[b];
  const float* lg = logits + (size_t)b * TT * TAGS;
  const int*   lab = labels + b * TT;
  float sc = 0.f;
  for (int t = lane; t < TT; t += 64) {
    if (t < len) {
      sc += lg[t * TAGS + lab[t]];
      if (t >= 1) sc += trans[lab[t - 1] * TAGS + lab[t]];
    }
  }
  for (int o = 32; o > 0; o >>= 1) sc += __shfl_down(sc, o);
  if (lane == 0) scbuf[b] = sc;
}

// ------- CRF forward: 64-lane segmented matrix-product scan, 1 wave per row -------
// alpha_t = alpha_{t-1} * M_t, M_t[i][j] = exp(T[i][j]) * eu_t[j].
// Lane λ: product over t in [1+8λ, 1+8λ+8); then shfl_xor butterfly combine.
__global__ __launch_bounds__(256, 1) void k_crf2(const float* __restrict__ euk,
                                                 const float* __restrict__ scbuf,
                                                 const int* __restrict__ lengths,
                                                 const float* __restrict__ trans,
                                                 float* __restrict__ out) {
  const int wv = threadIdx.x >> 6, lane = threadIdx.x & 63;
  const int b = blockIdx.x * 4 + wv;
  const float* ep = euk + (size_t)b * TT * 12;
  const int len = lengths[b];
  const int lim = (len < TT) ? len : TT;

  float Et[81];
  #pragma unroll
  for (int i = 0; i < 81; ++i) Et[i] = __expf(trans[i]);

  float P[81];
  float Ks = 0.f;
  int   E2 = 0;

  const int t0 = 1 + lane * 8;
  auto rec = [&](int t) { int tl = (t < TT) ? t : (TT - 1); return ep + (size_t)tl * 12; };

  const float* p0 = rec(t0);
  float4 A0 = *(const float4*)p0, A1 = *(const float4*)(p0 + 4), A2 = *(const float4*)(p0 + 8);
  const float* p1 = rec(t0 + 1);
  float4 B0 = *(const float4*)p1, B1 = *(const float4*)(p1 + 4), B2 = *(const float4*)(p1 + 8);

  // s = 0: init P = upd ? M : I
  {
    float eu[9] = {A0.x, A0.y, A0.z, A0.w, A1.x, A1.y, A1.z, A1.w, A2.x};
    bool upd = t0 < lim;
    #pragma unroll
    for (int i = 0; i < 9; ++i)
      #pragma unroll
      for (int j = 0; j < 9; ++j)
        P[i * 9 + j] = upd ? Et[i * 9 + j] * eu[j] : ((i == j) ? 1.f : 0.f);
    Ks += upd ? A2.y : 0.f;
    A0 = B0; A1 = B1; A2 = B2;
    const float* pn = rec(t0 + 2);
    B0 = *(const float4*)pn; B1 = *(const float4*)(pn + 4); B2 = *(const float4*)(pn + 8);
  }

  for (int s = 1; s < 8; ++s) {
    float eu[9] = {A0.x, A0.y, A0.z, A0.w, A1.x, A1.y, A1.z, A1.w, A2.x};
    float mt = A2.y;
    bool upd = (t0 + s) < lim;
    A0 = B0; A1 = B1; A2 = B2;
    const float* pn = rec(t0 + s + 2);
    B0 = *(const float4*)pn; B1 = *(const float4*)(pn + 4); B2 = *(const float4*)(pn + 8);
    #pragma unroll
    for (int i = 0; i < 9; ++i) {
      float tmp[9];
      #pragma unroll
      for (int j = 0; j < 9; ++j) {
        float a = P[i * 9 + 0] * Et[0 * 9 + j];
        #pragma unroll
        for (int k = 1; k < 9; ++k) a = fmaf(P[i * 9 + k], Et[k * 9 + j], a);
        tmp[j] = a * eu[j];
      }
      #pragma unroll
      for (int j = 0; j < 9; ++j) P[i * 9 + j] = upd ? tmp[j] : P[i * 9 + j];
    }
    Ks += upd ? mt : 0.f;
  }

  // renorm (exact pow2)
  {
    float m = P[0];
    #pragma unroll
    for (int e = 1; e < 81; ++e) m = fmaxf(m, P[e]);
    int ex; frexpf(m, &ex);
    #pragma unroll
    for (int e = 0; e < 81; ++e) P[e] = ldexpf(P[e], -ex);
    E2 += ex;
  }

  // butterfly combine (order-preserving): 6 levels
  for (int d = 0; d < 6; ++d) {
    int msk = 1 << d;
    float Q[81];
    #pragma unroll
    for (int e = 0; e < 81; ++e) Q[e] = __shfl_xor(P[e], msk);
    int   E2p = __shfl_xor(E2, msk);
    float Ksp = __shfl_xor(Ks, msk);
    bool late = (lane & msk) != 0;
    #pragma unroll
    for (int e = 0; e < 81; ++e) {   // if late: (P,Q) <- (Q,P) so result = earlier*later
      float a = P[e], q = Q[e];
      P[e] = late ? q : a;
      Q[e] = late ? a : q;
    }
    #pragma unroll
    for (int i = 0; i < 9; ++i) {
      float tmp[9];
      #pragma unroll
      for (int j = 0; j < 9; ++j) {
        float a = P[i * 9 + 0] * Q[0 * 9 + j];
        #pragma unroll
        for (int k = 1; k < 9; ++k) a = fmaf(P[i * 9 + k], Q[k * 9 + j], a);
        tmp[j] = a;
      }
      #pragma unroll
      for (int j = 0; j < 9; ++j) P[i * 9 + j] = tmp[j];
    }
    E2 += E2p; Ks += Ksp;
    float m = P[0];
    #pragma unroll
    for (int e = 1; e < 81; ++e) m = fmaxf(m, P[e]);
    int ex; frexpf(m, &ex);
    #pragma unroll
    for (int e = 0; e < 81; ++e) P[e] = ldexpf(P[e], -ex);
    E2 += ex;
  }

  // epilogue: alpha = eu0 * P_total; log-norm; output
  float4 z0 = *(const float4*)ep, z1 = *(const float4*)(ep + 4), z2 = *(const float4*)(ep + 8);
  float eu0[9] = {z0.x, z0.y, z0.z, z0.w, z1.x, z1.y, z1.z, z1.w, z2.x};
  float alpha[9];
  #pragma unroll
  for (int j = 0; j < 9; ++j) {
    float a = eu0[0] * P[0 * 9 + j];
    #pragma unroll
    for (int i = 1; i < 9; ++i) a = fmaf(eu0[i], P[i * 9 + j], a);
    alpha[j] = a;
  }
  float S = ((alpha[0] + alpha[1]) + (alpha[2] + alpha[3])) +
            ((alpha[4] + alpha[5]) + (alpha[6] + alpha[7])) + alpha[8];
  float ln = logf(S) + (float)E2 * 0.69314718056f + Ks + z2.y;
  if (lane == 0) out[b] = (len > 0) ? (scbuf[b] - ln) : 0.f;
}

__global__ void k_copy_trans(const float* __restrict__ trans, float* __restrict__ out) {
  int i = threadIdx.x;
  if (i < TAGS * TAGS) out[BB + i] = trans[i];
}

extern "C" void kernel_launch(void* const* d_in, const int* in_sizes, int n_in,
                              void* d_out, int out_size, void* d_ws, size_t ws_size,
                              hipStream_t stream) {
  const int*   inp    = (const int*)d_in[0];
  const float* ch     = (const float*)d_in[1];
  const int*   labels = (const int*)d_in[2];
  const float* E      = (const float*)d_in[3];
  const float* Wx_f   = (const float*)d_in[4];
  const float* Wh_f   = (const float*)d_in[5];
  const float* b_f    = (const float*)d_in[6];
  const float* Wx_b   = (const float*)d_in[7];
  const float* Wh_b   = (const float*)d_in[8];
  const float* b_b    = (const float*)d_in[9];
  const float* Wd     = (const float*)d_in[10];
  const float* bd     = (const float*)d_in[11];
  const float* trans  = (const float*)d_in[12];
  float* out = (float*)d_out;

  unsigned short* x    = (unsigned short*)d_ws;                 // 33.55 MB
  unsigned short* hseq = x + (size_t)BB * TT * 128;             // 67.11 MB
  unsigned short* WxT  = hseq + (size_t)2 * BB * TT * 128;      // 0.26 MB
  unsigned short* WhT  = WxT + 2 * NG * 128;                    // 0.26 MB
  unsigned short* WdT  = WhT + 2 * NG * 128;                    // 8 KB
  float* logits        = (float*)(WdT + 16 * 256);              // 4.72 MB
  float* euk           = logits + (size_t)BB * TT * TAGS;       // 6.29 MB
  float* cbuf          = euk + (size_t)BB * TT * 12;            // 0.26 MB
  float* scbuf         = cbuf + (size_t)2 * BB * RNN;           // 1 KB
  int*   lengths       = (int*)(scbuf + BB);                    // 1 KB
  unsigned short* zbuf = (unsigned short*)(lengths + 256);      // 2 * L/2 MB (bf16)

  const size_t zoff = (size_t)((char*)zbuf - (char*)d_ws);
  int NP = 4;
  const int cands[4] = {4, 8, 16, 32};
  for (int i = 0; i < 4; ++i) {
    NP = cands[i];
    if (zoff + 2ull * (size_t)(TT / NP) * 524288ull <= ws_size) break;
  }
  const int L = TT / NP;
  const size_t zsl = (size_t)L * 262144;  // bf16 elements per slice

  k_build_x<<<(BB * TT * 128) / 256, 256, 0, stream>>>(inp, ch, E, x);
  k_prep_w<<<513, 256, 0, stream>>>(Wx_f, Wh_f, Wx_b, Wh_b, Wd, WxT, WhT, WdT);
  k_lengths<<<BB, 64, 0, stream>>>(labels, lengths);

  // prologue: produce z for pass 0
  k_fused<<<2 * 16 * (L / 16), 512, 0, stream>>>(x, WxT, WhT, b_f, b_b,
                                                 zbuf, zbuf, hseq, cbuf,
                                                 0, 0, 0, 1, 0, L);
  for (int p = 0; p < NP; ++p) {
    int nz = (p + 1 < NP) ? 2 * 16 * (L / 16) : 0;
    k_fused<<<64 + nz, 512, 0, stream>>>(
        x, WxT, WhT, b_f, b_b,
        zbuf + (size_t)(p & 1) * zsl,
        zbuf + (size_t)((p + 1) & 1) * zsl,
        hseq, cbuf,
        64, p * L, (p + 1) * L, (p == 0) ? 1 : 0, (p + 1) * L, nz ? L : 0);
  }

  k_logits<<<(BB * TT) / 256, 256, 0, stream>>>(hseq, WdT, bd, logits, euk);
  k_score<<<BB, 64, 0, stream>>>(logits, labels, lengths, trans, scbuf);
  k_crf2<<<BB / 4, 256, 0, stream>>>(euk, scbuf, lengths, trans, out);
  k_copy_trans<<<1, 128, 0, stream>>>(trans, out);
}